// Round 2
// baseline (287.513 us; speedup 1.0000x reference)
//
#include <hip/hip_runtime.h>
#include <hip/hip_bf16.h>

#define BB   32768
#define LL   1024
#define FEA  1028
#define MEM  50
#define DATE 32

typedef float  f32x4  __attribute__((ext_vector_type(4)));
typedef __bf16 bf16x8 __attribute__((ext_vector_type(8)));

__device__ __forceinline__ float wave_max(float v) {
    #pragma unroll
    for (int off = 32; off; off >>= 1) v = fmaxf(v, __shfl_xor(v, off));
    return v;
}
__device__ __forceinline__ float wave_sum(float v) {
    #pragma unroll
    for (int off = 32; off; off >>= 1) v += __shfl_xor(v, off);
    return v;
}
// tanh via __expf: exact at both saturations, ~1e-6 abs error in between.
__device__ __forceinline__ float fast_tanh(float v) {
    float e = __expf(2.f * v);
    return 1.f - 2.f / (e + 1.f);
}

// ---------------- K1: read-streaming kernel -------------------------------
// blocks [0, 2048): weight/bias GEMV over x (16 rows/block, 4 rows/wave).
//   Pure read stream: 16 independent 1KB loads in flight per wave, one
//   interleaved butterfly pair, fast tanh, 2 scalar stores per row.
// blocks [2048, 2304): fold transposed-conv into memory matrix:
//   wc[n*64+k] = sum_j convt_w[j] * mem_W[k][n+4-j], zero-padded k in [50,64)
__global__ __launch_bounds__(256) void prep_and_wb(
        const float* __restrict__ convt_w,
        const float* __restrict__ mem_W,
        const float* __restrict__ x,
        const float* __restrict__ fcw_w, const float* __restrict__ fcw_b,
        const float* __restrict__ fcb_w, const float* __restrict__ fcb_b,
        __bf16* __restrict__ wc,
        float* __restrict__ out) {
    if (blockIdx.x >= 2048) {
        int idx = (blockIdx.x - 2048) * 256 + threadIdx.x;   // 65536
        int n = idx >> 6, k = idx & 63;
        float acc = 0.f;
        if (k < MEM) {
            #pragma unroll
            for (int j = 0; j < 5; ++j)
                acc += convt_w[j] * mem_W[k * FEA + n + 4 - j];
        }
        wc[n * 64 + k] = (__bf16)acc;
        return;
    }

    const int lane = threadIdx.x & 63;
    const int wid  = threadIdx.x >> 6;
    const int b0   = blockIdx.x * 16;

    f32x4 wv[4], bv[4];
    #pragma unroll
    for (int c = 0; c < 4; ++c) {
        wv[c] = *(const f32x4*)(fcw_w + c * 256 + lane * 4);
        bv[c] = *(const f32x4*)(fcb_w + c * 256 + lane * 4);
    }
    f32x4 xv[4][4];
    #pragma unroll
    for (int rr = 0; rr < 4; ++rr)
        #pragma unroll
        for (int c = 0; c < 4; ++c)
            xv[rr][c] = *(const f32x4*)(x + (size_t)(b0 + wid * 4 + rr) * LL
                                          + c * 256 + lane * 4);
    float fwb = fcw_b[0], fbb = fcb_b[0];
    #pragma unroll
    for (int rr = 0; rr < 4; ++rr) {
        int r = wid * 4 + rr;
        float aw = 0.f, ab = 0.f;
        #pragma unroll
        for (int c = 0; c < 4; ++c)
            #pragma unroll
            for (int j = 0; j < 4; ++j) {
                aw += xv[rr][c][j] * wv[c][j];
                ab += xv[rr][c][j] * bv[c][j];
            }
        #pragma unroll
        for (int off = 1; off <= 32; off <<= 1) {
            aw += __shfl_xor(aw, off);
            ab += __shfl_xor(ab, off);
        }
        if (lane == 0) {
            out[(size_t)BB * LL + (b0 + r)]      = fast_tanh(aw + fwb) * 0.5f + 1.0f;
            out[(size_t)BB * LL + BB + (b0 + r)] = fast_tanh(ab + fbb) * 0.5f;
        }
    }
}

// ---------------- K2: write-streaming kernel -------------------------------
// att softmax -> MFMA against folded wc -> LDS-staged row-contiguous NT stores.
// Reads only dv/dW/wc/w/b (all small or L2-hot); writes the 134 MB out tensor.
__global__ __launch_bounds__(256) void memconv_main(
        const float* __restrict__ dv,
        const float* __restrict__ dW,
        const __bf16* __restrict__ wc,
        float* __restrict__ out) {
    __shared__ __bf16 att_s[16 * 72];          // [row][k], 144B stride
    __shared__ float  w_s[16], b_s[16];
    __shared__ float  stage[4][16 * 72];       // per-wave D staging

    const int lane = threadIdx.x & 63;
    const int wid  = threadIdx.x >> 6;
    const int cg   = lane & 15;
    const int kg   = lane >> 4;
    const int b0   = blockIdx.x * 16;

    // w/b readback for this block's 16 rows (written by prep_and_wb)
    if (threadIdx.x < 16) {
        w_s[threadIdx.x] = out[(size_t)BB * LL + b0 + threadIdx.x];
        b_s[threadIdx.x] = out[(size_t)BB * LL + BB + b0 + threadIdx.x];
    }

    // ---- Phase 0: att for rows wid*4 .. wid*4+3 ----
    {
        int m = lane < MEM ? lane : MEM - 1;
        float dwv[DATE];
        const f32x4* dwp = (const f32x4*)(dW + m * DATE);
        #pragma unroll
        for (int c = 0; c < 8; ++c) {
            f32x4 v = dwp[c];
            #pragma unroll
            for (int j = 0; j < 4; ++j) dwv[c * 4 + j] = v[j];
        }
        #pragma unroll
        for (int rr = 0; rr < 4; ++rr) {
            int r = wid * 4 + rr;
            const f32x4* dvp = (const f32x4*)(dv + (size_t)(b0 + r) * DATE);
            float sc = 0.f;
            #pragma unroll
            for (int c = 0; c < 8; ++c) {
                f32x4 v = dvp[c];
                #pragma unroll
                for (int j = 0; j < 4; ++j) sc += v[j] * dwv[c * 4 + j];
            }
            float scm = (lane < MEM) ? sc : -1e30f;
            float mx  = wave_max(scm);
            float e   = (lane < MEM) ? __expf(sc - mx) : 0.f;
            float s   = wave_sum(e);
            float p   = e / s;
            float d   = p - 0.0025f;
            float p2  = (d > 0.f) ? p * d / (d + 1e-12f) : 0.f;
            float s2  = wave_sum(p2) + 1e-12f;
            float att = p2 / s2;
            att_s[r * 72 + lane] = (lane < MEM) ? (__bf16)att : (__bf16)0.f;
        }
    }
    __syncthreads();

    // ---- Phase B: transposed-operand MFMA + LDS-staged contiguous NT stores ----
    // A = wc (m = n-dim), B = att (col = batch). D[n kg*4+j][batch cg].
    {
        bf16x8 bfr0 = *(const bf16x8*)(att_s + cg * 72 + kg * 8);
        bf16x8 bfr1 = *(const bf16x8*)(att_s + cg * 72 + 32 + kg * 8);
        float* st = stage[wid];
        const int n0 = wid * 256;
        #pragma unroll
        for (int R = 0; R < 4; ++R) {
            // compute 4 tiles (64 n-columns), stage D into LDS
            #pragma unroll
            for (int t = 0; t < 4; ++t) {
                int n = n0 + (R * 4 + t) * 16 + cg;
                bf16x8 a0 = *(const bf16x8*)(wc + n * 64 + kg * 8);
                bf16x8 a1 = *(const bf16x8*)(wc + n * 64 + 32 + kg * 8);
                f32x4 acc = {0.f, 0.f, 0.f, 0.f};
                acc = __builtin_amdgcn_mfma_f32_16x16x32_bf16(a0, bfr0, acc, 0, 0, 0);
                acc = __builtin_amdgcn_mfma_f32_16x16x32_bf16(a1, bfr1, acc, 0, 0, 0);
                *(f32x4*)(st + cg * 72 + t * 16 + kg * 4) = acc;
            }
            // flush: row-contiguous, 4x 256B segments per inst, nontemporal
            // (keeps x L3-resident: x + out = 268MB > 256MB L3 otherwise)
            #pragma unroll
            for (int j = 0; j < 4; ++j) {
                int row = j * 4 + (lane >> 4);
                int nl  = (lane & 15) * 4;
                f32x4 v = *(const f32x4*)(st + row * 72 + nl);
                float w = w_s[row], bi = b_s[row];
                f32x4 o;
                #pragma unroll
                for (int k = 0; k < 4; ++k) o[k] = v[k] * w + bi;
                __builtin_nontemporal_store(
                    o, (f32x4*)(out + (size_t)(b0 + row) * LL + n0 + R * 64 + nl));
            }
        }
    }
}

extern "C" void kernel_launch(void* const* d_in, const int* in_sizes, int n_in,
                              void* d_out, int out_size, void* d_ws, size_t ws_size,
                              hipStream_t stream) {
    const float* x     = (const float*)d_in[0];
    const float* dv    = (const float*)d_in[1];
    // d_in[2] = conv_w: DEAD CODE in the reference (st is overwritten by st_mem)
    const float* convt = (const float*)d_in[3];
    const float* memW  = (const float*)d_in[4];
    const float* dateW = (const float*)d_in[5];
    const float* fcww  = (const float*)d_in[6];
    const float* fcwb  = (const float*)d_in[7];
    const float* fcbw  = (const float*)d_in[8];
    const float* fcbb  = (const float*)d_in[9];
    float* out = (float*)d_out;
    __bf16* wc = (__bf16*)d_ws;   // 64K bf16 = 128 KB

    prep_and_wb <<<2304,    256, 0, stream>>>(convt, memW, x, fcww, fcwb, fcbw, fcbb, wc, out);
    memconv_main<<<BB / 16, 256, 0, stream>>>(dv, dateW, wc, out);
}